// Round 7
// baseline (214.460 us; speedup 1.0000x reference)
//
#include <hip/hip_runtime.h>

#define EPS 1e-8f
#define LN_EPS 1e-5f
#define NROWS 8192
#define SLEN 4096
#define PROBS_OFF 2097152   // 8192*256
#define RPB 16              // rows per block (= one head group)

typedef __attribute__((ext_vector_type(8))) short bf16x8;
typedef __attribute__((ext_vector_type(4))) float f32x4;

__device__ __forceinline__ short f2bf(float f) {
    unsigned u = __float_as_uint(f);
    unsigned r = (u + 0x7FFFu + ((u >> 16) & 1u)) >> 16;  // RNE
    return (short)r;
}

// async 16B global->LDS DMA: LDS dest = wave-uniform base + lane*16 (linear);
// global source is per-lane, so swizzled layouts come from pre-swizzling the
// source index (G21: both-sides-or-neither).
__device__ __forceinline__ void g2l16(const float4* g, float4* l) {
    __builtin_amdgcn_global_load_lds(
        (const __attribute__((address_space(1))) unsigned int*)g,
        (__attribute__((address_space(3))) unsigned int*)l,
        16, 0, 0);
}

// octet-local XOR slot swizzle (involution): spreads the stride-4-slot window
// reads across bank-quads (8-way conflict -> 2-way = free). Slots 0..7 are
// fixpoints so the zero head survives.
__device__ __forceinline__ int swz(int s) { return s ^ ((s >> 3) & 7); }

// ---------------- fused kernel: 512 blocks x 16 rows, feat pipeline + head ----------------
// Per block: 3-deep DMA pipeline over its 16 rows (counted vmcnt(8) waits —
// rows r+1, r+2 stay in flight across barriers; never drain to 0 in the loop).
// Thread t owns elements [16t,16t+16) of the current row; 20-float history via
// zero-headed swizzled LDS. t255 finishes each row's 4 features into comb[].
// Head phase (encoder+LN+MFMA+softmax) then runs in-block — no second kernel,
// no ws, no cross-block coherence.
__global__ __launch_bounds__(256) void k_fused(
    const float* __restrict__ prices, float* __restrict__ out,
    const float* __restrict__ enc_w, const float* __restrict__ enc_b,
    const float* __restrict__ enc_g, const float* __restrict__ enc_bt,
    const float* __restrict__ w1, const float* __restrict__ b1,
    const float* __restrict__ w2, const float* __restrict__ b2)
{
    __shared__ float4 sbuf[3][1032];          // 49.5 KB: 3-deep row buffers
    __shared__ float red[4][3];
    __shared__ __align__(16) float comb[RPB][4];
    __shared__ short rfb[RPB][264];           // bf16 rf tile, +8 pad
    __shared__ float hbuf[RPB][68];           // padded

    const int t = threadIdx.x;
    const int lane = t & 63, wv = t >> 6;
    const int r0 = blockIdx.x * RPB;

    // stage row r into buffer bi: linear LDS dest, pre-swizzled global source
    auto stage = [&](int r, int bi) {
        const float4* R4 = (const float4*)prices + (size_t)(r0 + r) * 1024;
        #pragma unroll
        for (int k = 0; k < 4; ++k) {
            const int base = 8 + 256 * k + 64 * wv;
            const int g = swz(base + lane) - 8;
            g2l16(R4 + g, &sbuf[bi][base]);
        }
    };

    float pm10_l = 0.f, plast_l = 0.f;   // t255 carries the current row's tails

    // per-row compute: partial S,Q,T -> red[][] (lane0); t255 grabs tails
    auto compute_row = [&](int bi) {
        float4 q0 = sbuf[bi][swz(4 * t + 3)];
        float4 q1 = sbuf[bi][swz(4 * t + 4)];
        float4 q2 = sbuf[bi][swz(4 * t + 5)];
        float4 q3 = sbuf[bi][swz(4 * t + 6)];
        float4 q4 = sbuf[bi][swz(4 * t + 7)];
        float4 s0 = sbuf[bi][swz(4 * t + 8)];
        float4 s1 = sbuf[bi][swz(4 * t + 9)];
        float4 s2 = sbuf[bi][swz(4 * t + 10)];
        float4 s3 = sbuf[bi][swz(4 * t + 11)];

        float xv[16] = { s0.x, s0.y, s0.z, s0.w, s1.x, s1.y, s1.z, s1.w,
                         s2.x, s2.y, s2.z, s2.w, s3.x, s3.y, s3.z, s3.w };
        float ov[16] = { q0.x, q0.y, q0.z, q0.w, q1.x, q1.y, q1.z, q1.w,
                         q2.x, q2.y, q2.z, q2.w, q3.x, q3.y, q3.z, q3.w };

        float W = q0.y + q0.z + q0.w
                + q1.x + q1.y + q1.z + q1.w
                + q2.x + q2.y + q2.z + q2.w
                + q3.x + q3.y + q3.z + q3.w
                + q4.x + q4.y + q4.z + q4.w;

        float sum = 0.0f, sq = 0.0f, ts = 0.0f;
        if (t >= 2) {
            #pragma unroll
            for (int j = 0; j < 16; ++j) {
                float x = xv[j];
                W += (j == 0) ? x : (x - ov[j]);
                sum += x;
                sq = fmaf(x, x, sq);
                // (x - W/20)/(W/20+EPS) == (x*20 - W)/(W + 20*EPS)
                float num = fmaf(x, 20.0f, -W);
                float den = W + (20.0f * EPS);
                ts += num * __builtin_amdgcn_rcpf(den);
            }
        } else {
            const float pf = (float)(16 * t);
            #pragma unroll
            for (int j = 0; j < 16; ++j) {
                float x = xv[j];
                W += (j == 0) ? x : (x - ov[j]);
                sum += x;
                sq = fmaf(x, x, sq);
                float c = fminf(pf + (float)(j + 1), 20.0f);
                float num = fmaf(x, c, -W);
                float den = fmaf(EPS, c, W);
                ts += num * __builtin_amdgcn_rcpf(den);
            }
        }
        if (t == 255) { pm10_l = s1.z; plast_l = s3.w; }  // els 4086, 4095

        #pragma unroll
        for (int off = 32; off > 0; off >>= 1) {
            sum += __shfl_xor(sum, off);
            sq  += __shfl_xor(sq,  off);
            ts  += __shfl_xor(ts,  off);
        }
        if (lane == 0) { red[wv][0] = sum; red[wv][1] = sq; red[wv][2] = ts; }
    };

    // t255 combines wave partials (after barrier) into comb[r]
    auto finish_row = [&](int r) {
        if (t == 255) {
            float S = red[0][0] + red[1][0] + red[2][0] + red[3][0];
            float Q = red[0][1] + red[1][1] + red[2][1] + red[3][1];
            float T = red[0][2] + red[1][2] + red[2][2] + red[3][2];
            float mean = S * (1.0f / 4096.0f);
            float var  = fmaxf((Q - 4096.0f * mean * mean) * (1.0f / 4095.0f), 0.0f);
            comb[r][0] = T * (1.0f / 4096.0f);
            comb[r][1] = (plast_l - pm10_l) / (pm10_l + EPS);
            comb[r][2] = (plast_l - mean) / (mean + EPS);
            comb[r][3] = sqrtf(var) / (mean + EPS);
        }
    };

    // prologue: zero heads (swz fixpoints), pre-stage rows 0,1
    if (t < 8) {
        const float4 z4 = make_float4(0.f, 0.f, 0.f, 0.f);
        sbuf[0][t] = z4; sbuf[1][t] = z4; sbuf[2][t] = z4;
    }
    stage(0, 0);
    stage(1, 1);

    // main pipeline: rows 0..13 with 2 rows in flight (vmcnt(8) = 2x4 loads)
    for (int r = 0; r < RPB - 2; ++r) {
        stage(r + 2, (r + 2) % 3);
        asm volatile("s_waitcnt vmcnt(8) lgkmcnt(0)\ns_barrier" ::: "memory");
        __builtin_amdgcn_sched_barrier(0);
        compute_row(r % 3);
        asm volatile("s_waitcnt lgkmcnt(0)\ns_barrier" ::: "memory");
        finish_row(r);
    }
    // row 14: one row still in flight
    asm volatile("s_waitcnt vmcnt(4) lgkmcnt(0)\ns_barrier" ::: "memory");
    __builtin_amdgcn_sched_barrier(0);
    compute_row((RPB - 2) % 3);
    asm volatile("s_waitcnt lgkmcnt(0)\ns_barrier" ::: "memory");
    finish_row(RPB - 2);
    // row 15: drain
    asm volatile("s_waitcnt vmcnt(0) lgkmcnt(0)\ns_barrier" ::: "memory");
    __builtin_amdgcn_sched_barrier(0);
    compute_row((RPB - 1) % 3);
    asm volatile("s_waitcnt lgkmcnt(0)\ns_barrier" ::: "memory");
    finish_row(RPB - 1);

    // ---------------- head phase (same block) ----------------
    const int l15 = lane & 15, q = lane >> 4;
    const int wave = wv;

    // B-frags: wave w owns cols [16w,16w+16); n=lane&15, k=q*8+j per k-tile
    bf16x8 bfrag[8];
    #pragma unroll
    for (int kt = 0; kt < 8; ++kt) {
        #pragma unroll
        for (int j = 0; j < 8; ++j) {
            int k = kt * 32 + q * 8 + j;
            bfrag[kt][j] = f2bf(w1[k * 64 + wave * 16 + l15]);
        }
    }
    const float ew0  = enc_w[wave * 256 + lane];
    const float ew1v = enc_w[wave * 256 + 64 + lane];
    const float ew2v = enc_w[wave * 256 + 128 + lane];
    const float ew3v = enc_w[wave * 256 + 192 + lane];
    const float ebv = enc_b[t], egv = enc_g[t], btv = enc_bt[t];

    __syncthreads();   // comb[] fully visible

    // encoder + relu + LayerNorm; 2 rows/iter for ILP on the shuffle chains
    for (int r = 0; r < RPB; r += 2) {
        float4 cba = *(const float4*)comb[r];
        float4 cbb = *(const float4*)comb[r + 1];
        float va = fmaf(cba.x, ew0, fmaf(cba.y, ew1v, fmaf(cba.z, ew2v, fmaf(cba.w, ew3v, ebv))));
        float vb = fmaf(cbb.x, ew0, fmaf(cbb.y, ew1v, fmaf(cbb.z, ew2v, fmaf(cbb.w, ew3v, ebv))));
        va = fmaxf(va, 0.0f);
        vb = fmaxf(vb, 0.0f);
        float sma = va, smb = vb;
        #pragma unroll
        for (int off = 32; off > 0; off >>= 1) {
            sma += __shfl_xor(sma, off);
            smb += __shfl_xor(smb, off);
        }
        float mua = sma * (1.0f / 64.0f);
        float mub = smb * (1.0f / 64.0f);
        float da = va - mua, db = vb - mub;
        float vsa = da * da, vsb = db * db;
        #pragma unroll
        for (int off = 32; off > 0; off >>= 1) {
            vsa += __shfl_xor(vsa, off);
            vsb += __shfl_xor(vsb, off);
        }
        float ya = fmaf(da * rsqrtf(vsa * (1.0f / 64.0f) + LN_EPS), egv, btv);
        float yb = fmaf(db * rsqrtf(vsb * (1.0f / 64.0f) + LN_EPS), egv, btv);
        out[(size_t)(r0 + r) * 256 + t] = ya;       // regime_features fp32
        out[(size_t)(r0 + r + 1) * 256 + t] = yb;
        rfb[r][t] = f2bf(ya);
        rfb[r + 1][t] = f2bf(yb);
    }
    __syncthreads();

    // h = rf @ w1 via 16x16x32 bf16 MFMA; single m-tile (16 rows)
    f32x4 acc0 = {0.f, 0.f, 0.f, 0.f};
    #pragma unroll
    for (int kt = 0; kt < 8; ++kt) {
        bf16x8 a0 = *(const bf16x8*)&rfb[l15][kt * 32 + q * 8];
        acc0 = __builtin_amdgcn_mfma_f32_16x16x32_bf16(a0, bfrag[kt], acc0, 0, 0, 0);
    }

    const int col = wave * 16 + l15;
    const float b1v = b1[col];
    #pragma unroll
    for (int rg = 0; rg < 4; ++rg)
        hbuf[q * 4 + rg][col] = fmaxf(acc0[rg] + b1v, 0.0f);
    __syncthreads();

    // logits + softmax (quad per row); 4 independent fmaf chains
    if (t < 4 * RPB) {
        int r = t >> 2, c = t & 3;
        float a0 = 0.f, a1 = 0.f, a2 = 0.f, a3 = 0.f;
        #pragma unroll
        for (int j = 0; j < 16; ++j) {
            a0 = fmaf(hbuf[r][j],      w2[j * 4 + c],        a0);
            a1 = fmaf(hbuf[r][16 + j], w2[(16 + j) * 4 + c], a1);
            a2 = fmaf(hbuf[r][32 + j], w2[(32 + j) * 4 + c], a2);
            a3 = fmaf(hbuf[r][48 + j], w2[(48 + j) * 4 + c], a3);
        }
        float lg = b2[c] + ((a0 + a1) + (a2 + a3));
        float mx = fmaxf(lg, __shfl_xor(lg, 1, 4));
        mx = fmaxf(mx, __shfl_xor(mx, 2, 4));
        float ex = __expf(lg - mx);
        float s2 = ex + __shfl_xor(ex, 1, 4);
        s2 += __shfl_xor(s2, 2, 4);
        out[PROBS_OFF + (size_t)(r0 + r) * 4 + c] = ex / s2;
    }
}

extern "C" void kernel_launch(void* const* d_in, const int* in_sizes, int n_in,
                              void* d_out, int out_size, void* d_ws, size_t ws_size,
                              hipStream_t stream) {
    const float* prices  = (const float*)d_in[0];
    const float* enc_w   = (const float*)d_in[1];
    const float* enc_b   = (const float*)d_in[2];
    const float* enc_g   = (const float*)d_in[3];
    const float* enc_bt  = (const float*)d_in[4];
    const float* head_w1 = (const float*)d_in[5];
    const float* head_b1 = (const float*)d_in[6];
    const float* head_w2 = (const float*)d_in[7];
    const float* head_b2 = (const float*)d_in[8];
    float* out = (float*)d_out;
    (void)d_ws; (void)ws_size;

    k_fused<<<NROWS / RPB, 256, 0, stream>>>(prices, out, enc_w, enc_b, enc_g,
                                             enc_bt, head_w1, head_b1, head_w2,
                                             head_b2);
}

// Round 8
// 212.906 us; speedup vs baseline: 1.0073x; 1.0073x over previous
//
#include <hip/hip_runtime.h>

#define EPS 1e-8f
#define LN_EPS 1e-5f
#define NROWS 8192
#define SLEN 4096
#define PROBS_OFF 2097152   // 8192*256
#define RPB 16              // rows per block; 4 waves x 4 rows

typedef __attribute__((ext_vector_type(8))) short bf16x8;
typedef __attribute__((ext_vector_type(4))) float f32x4;

__device__ __forceinline__ short f2bf(float f) {
    unsigned u = __float_as_uint(f);
    unsigned r = (u + 0x7FFFu + ((u >> 16) & 1u)) >> 16;  // RNE
    return (short)r;
}

// async 16B global->LDS DMA (LDS dest wave-uniform + lane*16; source per-lane)
__device__ __forceinline__ void g2l16(const float4* g, float4* l) {
    __builtin_amdgcn_global_load_lds(
        (const __attribute__((address_space(1))) unsigned int*)g,
        (__attribute__((address_space(3))) unsigned int*)l,
        16, 0, 0);
}

// octet-local XOR slot swizzle (involution): spreads stride-4-slot window
// reads across bank quads (linear would be a same-quad pileup).
__device__ __forceinline__ int swz(int s) { return s ^ ((s >> 3) & 7); }

// ---------------- fused kernel: wave-autonomous streaming, zero feat barriers --------
// Each of 4 waves owns 4 whole rows = 16 chunks of 1024 elements. Per wave:
// 4 private LDS buffers (4 KB), stage-3-ahead via counted vmcnt (12 ops in
// flight), lane reads 5 hist + 4 own b128 slots per chunk, 16-el rolling-20
// loop accumulating row S/Q/T. History for a chunk's first 20 floats comes
// from the previous chunk's buffer (read before restaging, fenced by
// lgkmcnt+sched_barrier) or a per-wave zero block at row start. Row finish:
// 64-lane xor-reduce, lane 63 (holds p_m10/p_last) writes comb[]. No
// __syncthreads until the head phase.
__global__ __launch_bounds__(256) void k_fused(
    const float* __restrict__ prices, float* __restrict__ out,
    const float* __restrict__ enc_w, const float* __restrict__ enc_b,
    const float* __restrict__ enc_g, const float* __restrict__ enc_bt,
    const float* __restrict__ w1, const float* __restrict__ b1,
    const float* __restrict__ w2, const float* __restrict__ b2)
{
    __shared__ float4 sbuf[4][4][256];        // [wave][buf][slot]  64 KB
    __shared__ float4 zh[4][8];               // per-wave zero head 512 B
    __shared__ __align__(16) float comb[RPB][4];
    __shared__ short rfb[RPB][264];           // bf16 rf tile, +8 pad
    __shared__ float hbuf[RPB][68];           // padded

    const int t = threadIdx.x;
    const int lane = t & 63, wv = t >> 6;
    const int r0 = blockIdx.x * RPB;

    if (lane < 8) zh[wv][lane] = make_float4(0.f, 0.f, 0.f, 0.f);
    asm volatile("s_waitcnt lgkmcnt(0)" ::: "memory");

    const float4* rowbase = (const float4*)prices + (size_t)(r0 + 4 * wv) * 1024;

    // chunk g: row rr=g>>2, quarter h=g&3 -> buffer h; linear LDS dest,
    // pre-swizzled global source (G21 both-sides-or-neither)
    auto stage = [&](int g) {
        const float4* src = rowbase + (size_t)(g >> 2) * 1024 + (g & 3) * 256;
        float4* dst = &sbuf[wv][g & 3][0];
        #pragma unroll
        for (int k = 0; k < 4; ++k)
            g2l16(src + swz(64 * k + lane), dst + 64 * k);
    };

    stage(0); stage(1); stage(2);

    float S = 0.f, Q = 0.f, T = 0.f;

    #pragma unroll
    for (int g = 0; g < 16; ++g) {
        const int h = g & 3;
        // wait for chunk g only (g+1,g+2[,g+3] stay in flight; 4 ops/chunk)
        if (g <= 13)      asm volatile("s_waitcnt vmcnt(8)" ::: "memory");
        else if (g == 14) asm volatile("s_waitcnt vmcnt(4)" ::: "memory");
        else              asm volatile("s_waitcnt vmcnt(0)" ::: "memory");
        __builtin_amdgcn_sched_barrier(0);

        const float4* cur = &sbuf[wv][h][0];
        const float4* prv = &sbuf[wv][(g + 3) & 3][0];   // (g-1)&3

        // hist: logical slots 4*lane-5 .. 4*lane-1 (20 floats before own 16 els)
        float4 hq0, hq1, hq2, hq3, hq4;
        {
            const bool zrow = (h == 0);
            #pragma unroll
            for (int i = 0; i < 5; ++i) {
                int s = 4 * lane - 5 + i;
                const float4* bp = (s >= 0) ? cur : (zrow ? &zh[wv][0] : prv);
                int idx = (s >= 0) ? swz(s) : (zrow ? (s + 5) : swz(s + 256));
                float4 v = bp[idx];
                if (i == 0) hq0 = v; else if (i == 1) hq1 = v;
                else if (i == 2) hq2 = v; else if (i == 3) hq3 = v; else hq4 = v;
            }
        }
        float4 s0 = cur[swz(4 * lane)];
        float4 s1 = cur[swz(4 * lane + 1)];
        float4 s2 = cur[swz(4 * lane + 2)];
        float4 s3 = cur[swz(4 * lane + 3)];

        // all reads of cur/prv retired before restaging over them
        asm volatile("s_waitcnt lgkmcnt(0)" ::: "memory");
        __builtin_amdgcn_sched_barrier(0);
        if (g + 3 < 16) stage(g + 3);

        float xv[16] = { s0.x, s0.y, s0.z, s0.w, s1.x, s1.y, s1.z, s1.w,
                         s2.x, s2.y, s2.z, s2.w, s3.x, s3.y, s3.z, s3.w };
        float ov[16] = { hq0.x, hq0.y, hq0.z, hq0.w, hq1.x, hq1.y, hq1.z, hq1.w,
                         hq2.x, hq2.y, hq2.z, hq2.w, hq3.x, hq3.y, hq3.z, hq3.w };

        // sum of the 19 values preceding this lane's first element
        float W = hq0.y + hq0.z + hq0.w
                + hq1.x + hq1.y + hq1.z + hq1.w
                + hq2.x + hq2.y + hq2.z + hq2.w
                + hq3.x + hq3.y + hq3.z + hq3.w
                + hq4.x + hq4.y + hq4.z + hq4.w;

        const float pf = (float)(1024 * h + 16 * lane);   // row-local position
        #pragma unroll
        for (int j = 0; j < 16; ++j) {
            float x = xv[j];
            W += (j == 0) ? x : (x - ov[j]);
            S += x;
            Q = fmaf(x, x, Q);
            float c = fminf(pf + (float)(j + 1), 20.0f);
            // (x - W/c)/(W/c + EPS) == (x*c - W)/(W + EPS*c)   [c>0, W>=0.5]
            float num = fmaf(x, c, -W);
            float den = fmaf(EPS, c, W);
            T += num * __builtin_amdgcn_rcpf(den);
        }

        if (h == 3) {   // row finished: reduce + features
            float s_ = S, q_ = Q, t_ = T;
            #pragma unroll
            for (int off = 32; off > 0; off >>= 1) {
                s_ += __shfl_xor(s_, off);
                q_ += __shfl_xor(q_, off);
                t_ += __shfl_xor(t_, off);
            }
            if (lane == 63) {   // lane 63 holds row els 4080..4095
                float mean = s_ * (1.0f / 4096.0f);
                float var  = fmaxf((q_ - 4096.0f * mean * mean) * (1.0f / 4095.0f), 0.0f);
                float p_m10 = xv[6];    // el 4086
                float p_last = xv[15];  // el 4095
                float4 f;
                f.x = t_ * (1.0f / 4096.0f);
                f.y = (p_last - p_m10) / (p_m10 + EPS);
                f.z = (p_last - mean) / (mean + EPS);
                f.w = sqrtf(var) / (mean + EPS);
                *(float4*)comb[4 * wv + (g >> 2)] = f;
            }
            S = Q = T = 0.f;
        }
    }

    // ---------------- head phase (unchanged) ----------------
    const int l15 = lane & 15, qh = lane >> 4;
    const int wave = wv;

    bf16x8 bfrag[8];
    #pragma unroll
    for (int kt = 0; kt < 8; ++kt) {
        #pragma unroll
        for (int j = 0; j < 8; ++j) {
            int k = kt * 32 + qh * 8 + j;
            bfrag[kt][j] = f2bf(w1[k * 64 + wave * 16 + l15]);
        }
    }
    const float ew0  = enc_w[wave * 256 + lane];
    const float ew1v = enc_w[wave * 256 + 64 + lane];
    const float ew2v = enc_w[wave * 256 + 128 + lane];
    const float ew3v = enc_w[wave * 256 + 192 + lane];
    const float ebv = enc_b[t], egv = enc_g[t], btv = enc_bt[t];

    __syncthreads();   // all waves' comb[] visible

    for (int r = 0; r < RPB; r += 2) {
        float4 cba = *(const float4*)comb[r];
        float4 cbb = *(const float4*)comb[r + 1];
        float va = fmaf(cba.x, ew0, fmaf(cba.y, ew1v, fmaf(cba.z, ew2v, fmaf(cba.w, ew3v, ebv))));
        float vb = fmaf(cbb.x, ew0, fmaf(cbb.y, ew1v, fmaf(cbb.z, ew2v, fmaf(cbb.w, ew3v, ebv))));
        va = fmaxf(va, 0.0f);
        vb = fmaxf(vb, 0.0f);
        float sma = va, smb = vb;
        #pragma unroll
        for (int off = 32; off > 0; off >>= 1) {
            sma += __shfl_xor(sma, off);
            smb += __shfl_xor(smb, off);
        }
        float mua = sma * (1.0f / 64.0f);
        float mub = smb * (1.0f / 64.0f);
        float da = va - mua, db = vb - mub;
        float vsa = da * da, vsb = db * db;
        #pragma unroll
        for (int off = 32; off > 0; off >>= 1) {
            vsa += __shfl_xor(vsa, off);
            vsb += __shfl_xor(vsb, off);
        }
        float ya = fmaf(da * rsqrtf(vsa * (1.0f / 64.0f) + LN_EPS), egv, btv);
        float yb = fmaf(db * rsqrtf(vsb * (1.0f / 64.0f) + LN_EPS), egv, btv);
        out[(size_t)(r0 + r) * 256 + t] = ya;       // regime_features fp32
        out[(size_t)(r0 + r + 1) * 256 + t] = yb;
        rfb[r][t] = f2bf(ya);
        rfb[r + 1][t] = f2bf(yb);
    }
    __syncthreads();

    f32x4 acc0 = {0.f, 0.f, 0.f, 0.f};
    #pragma unroll
    for (int kt = 0; kt < 8; ++kt) {
        bf16x8 a0 = *(const bf16x8*)&rfb[l15][kt * 32 + qh * 8];
        acc0 = __builtin_amdgcn_mfma_f32_16x16x32_bf16(a0, bfrag[kt], acc0, 0, 0, 0);
    }

    const int col = wave * 16 + l15;
    const float b1v = b1[col];
    #pragma unroll
    for (int rg = 0; rg < 4; ++rg)
        hbuf[qh * 4 + rg][col] = fmaxf(acc0[rg] + b1v, 0.0f);
    __syncthreads();

    if (t < 4 * RPB) {
        int r = t >> 2, c = t & 3;
        float a0 = 0.f, a1 = 0.f, a2 = 0.f, a3 = 0.f;
        #pragma unroll
        for (int j = 0; j < 16; ++j) {
            a0 = fmaf(hbuf[r][j],      w2[j * 4 + c],        a0);
            a1 = fmaf(hbuf[r][16 + j], w2[(16 + j) * 4 + c], a1);
            a2 = fmaf(hbuf[r][32 + j], w2[(32 + j) * 4 + c], a2);
            a3 = fmaf(hbuf[r][48 + j], w2[(48 + j) * 4 + c], a3);
        }
        float lg = b2[c] + ((a0 + a1) + (a2 + a3));
        float mx = fmaxf(lg, __shfl_xor(lg, 1, 4));
        mx = fmaxf(mx, __shfl_xor(mx, 2, 4));
        float ex = __expf(lg - mx);
        float s2 = ex + __shfl_xor(ex, 1, 4);
        s2 += __shfl_xor(s2, 2, 4);
        out[PROBS_OFF + (size_t)(r0 + r) * 4 + c] = ex / s2;
    }
}

extern "C" void kernel_launch(void* const* d_in, const int* in_sizes, int n_in,
                              void* d_out, int out_size, void* d_ws, size_t ws_size,
                              hipStream_t stream) {
    const float* prices  = (const float*)d_in[0];
    const float* enc_w   = (const float*)d_in[1];
    const float* enc_b   = (const float*)d_in[2];
    const float* enc_g   = (const float*)d_in[3];
    const float* enc_bt  = (const float*)d_in[4];
    const float* head_w1 = (const float*)d_in[5];
    const float* head_b1 = (const float*)d_in[6];
    const float* head_w2 = (const float*)d_in[7];
    const float* head_b2 = (const float*)d_in[8];
    float* out = (float*)d_out;
    (void)d_ws; (void)ws_size;

    k_fused<<<NROWS / RPB, 256, 0, stream>>>(prices, out, enc_w, enc_b, enc_g,
                                             enc_bt, head_w1, head_b1, head_w2,
                                             head_b2);
}